// Round 3
// baseline (3753.352 us; speedup 1.0000x reference)
//
#include <hip/hip_runtime.h>

typedef unsigned short u16;
typedef __attribute__((ext_vector_type(8))) short short8v;    // MFMA A/B frag (8 bf16)
typedef __attribute__((ext_vector_type(8))) unsigned short ushort8v;
typedef __attribute__((ext_vector_type(4))) float f32x4;

__device__ __forceinline__ float bf2f(u16 u) {
    union { unsigned int i; float f; } v; v.i = ((unsigned int)u) << 16; return v.f;
}
__device__ __forceinline__ u16 f2bf(float f) {
    union { float f; unsigned int i; } v; v.f = f;
    unsigned int i = v.i;
    return (u16)((i + 0x7FFFu + ((i >> 16) & 1u)) >> 16);
}
__device__ __forceinline__ float leaky02(float x) { return x > 0.f ? x : 0.2f * x; }
// flag=1: input buffers are packed bf16; flag=0: fp32
__device__ __forceinline__ float load_in(const void* p, long i, int isbf) {
    return isbf ? bf2f(((const u16*)p)[i]) : ((const float*)p)[i];
}

// ---------------------------------------------------------------- dtype detect
__global__ void detect_kernel(const unsigned* __restrict__ w, int* __restrict__ flag) {
    __shared__ int cnt;
    int t = threadIdx.x;          // 256 threads
    if (t == 0) cnt = 0;
    __syncthreads();
    unsigned x = w[t * 16];       // sample 4096-word prefix (buffer >= 1.9M words)
    unsigned lo = x & 0xFFFFu;
    int e = (int)((x >> 7) & 0xFFu);
    int good = (lo == 0u) || (e >= 100 && e <= 140);
    atomicAdd(&cnt, good);
    __syncthreads();
    if (t == 0) *flag = (cnt > 128) ? 1 : 0;
}

// ---------------------------------------------------------------- CSR build
__global__ void hist_kernel(const int* __restrict__ ei, int* __restrict__ deg_src,
                            int* __restrict__ deg_dst, int E_) {
    int e = blockIdx.x * 256 + threadIdx.x;
    if (e >= E_) return;
    atomicAdd(&deg_src[ei[e]], 1);
    atomicAdd(&deg_dst[ei[E_ + e]], 1);
}

__global__ void scan_excl_kernel(const int* __restrict__ deg, int* __restrict__ ptr, int n) {
    __shared__ int s_woff[17];
    __shared__ int s_carry;
    const int t = threadIdx.x;          // 1024 threads
    const int lane = t & 63, wid = t >> 6;
    if (t == 0) s_carry = 0;
    __syncthreads();
    for (int base = 0; base < n; base += 1024) {
        int i = base + t;
        int v = (i < n) ? deg[i] : 0;
        int incl = v;
        #pragma unroll
        for (int d = 1; d < 64; d <<= 1) {
            int x = __shfl_up(incl, d, 64);
            if (lane >= d) incl += x;
        }
        if (lane == 63) s_woff[wid] = incl;
        __syncthreads();
        if (t == 0) {
            int run = 0;
            #pragma unroll
            for (int w = 0; w < 16; ++w) { int x = s_woff[w]; s_woff[w] = run; run += x; }
            s_woff[16] = run;
        }
        __syncthreads();
        int excl = s_carry + s_woff[wid] + incl - v;
        if (i < n) ptr[i] = excl;
        __syncthreads();
        if (t == 0) s_carry += s_woff[16];
        __syncthreads();
    }
    if (t == 0) ptr[n] = s_carry;
}

__global__ void copy2_kernel(const int* __restrict__ a, int* __restrict__ b,
                             const int* __restrict__ c, int* __restrict__ d2, int n) {
    int i = blockIdx.x * 256 + threadIdx.x;
    if (i < n) { b[i] = a[i]; d2[i] = c[i]; }
}

__global__ void fill_kernel(const int* __restrict__ ei, int* __restrict__ cur_src,
                            int* __restrict__ cur_dst, int* __restrict__ idx_src,
                            int* __restrict__ idx_dst, int E_) {
    int e = blockIdx.x * 256 + threadIdx.x;
    if (e >= E_) return;
    int s = ei[e], d = ei[E_ + e];
    int p = atomicAdd(&cur_dst[d], 1); idx_dst[p] = s;  // group by dst, store src
    int q = atomicAdd(&cur_src[s], 1); idx_src[q] = d;  // group by src, store dst
}

// ---------------------------------------------------------------- ingest (dtype-aware)
// src [K x Nc] row-major + element base -> dst [Nc x Kp] bf16, zero-pad k>=K
__global__ void ingest_transpose_kernel(const void* __restrict__ src, long base,
                                        u16* __restrict__ dst, int K, int Nc, int Kp,
                                        const int* __restrict__ flag) {
    int i = blockIdx.x * 256 + threadIdx.x;
    if (i >= Nc * Kp) return;
    int n = i / Kp, k = i - n * Kp;
    float v = (k < K) ? load_in(src, base + (long)k * Nc + n, *flag) : 0.f;
    dst[i] = f2bf(v);
}

__global__ void ingest_copy_kernel(const void* __restrict__ src, u16* __restrict__ dst,
                                   int n, const int* __restrict__ flag) {
    int i = blockIdx.x * 256 + threadIdx.x;
    if (i < n) dst[i] = f2bf(load_in(src, i, *flag));
}

// dst[r*ldd + c] = c<78 ? molx[r*78+c] : 0  for c in [0,96)
__global__ void ingest_pad_molx_kernel(const void* __restrict__ x, u16* __restrict__ dst,
                                       int ldd, int total, const int* __restrict__ flag) {
    int i = blockIdx.x * 256 + threadIdx.x;
    if (i >= total) return;
    int r = i / 96, c = i - r * 96;
    float v = (c < 78) ? load_in(x, (long)r * 78 + c, *flag) : 0.f;
    dst[(size_t)r * ldd + c] = f2bf(v);
}

// ---------------------------------------------------------------- GEMM (bf16 MFMA)
// C[Mp x Nc] = A[<=M x K] * Bt[Nc x K]^T (+C if beta); A-row reads clamped to M-1.
__global__ __launch_bounds__(256, 2)
void gemm_kernel(const u16* __restrict__ A, int lda,
                 const u16* __restrict__ Bt, int ldb,
                 u16* __restrict__ C, int ldc, int K, int M, int beta) {
    __shared__ __align__(16) u16 As[128 * 32];
    __shared__ __align__(16) u16 Bs[128 * 32];
    const int tid = threadIdx.x;
    const int wave = tid >> 6, lane = tid & 63;
    const int m0 = blockIdx.x * 128;
    const int n0 = blockIdx.y * 128;
    const int wm = (wave & 1) * 64, wn = (wave >> 1) * 64;
    const int r = lane & 15, q = lane >> 4;

    f32x4 acc[4][4];
    if (beta) {
        #pragma unroll
        for (int i = 0; i < 4; ++i)
            #pragma unroll
            for (int j = 0; j < 4; ++j)
                #pragma unroll
                for (int rr = 0; rr < 4; ++rr) {
                    size_t gr = (size_t)(m0 + wm + 16 * i + q * 4 + rr);
                    int gc = n0 + wn + 16 * j + r;
                    acc[i][j][rr] = bf2f(C[gr * ldc + gc]);
                }
    } else {
        #pragma unroll
        for (int i = 0; i < 4; ++i)
            #pragma unroll
            for (int j = 0; j < 4; ++j) acc[i][j] = (f32x4)0.f;
    }

    const int rowT = wave * 16 + (lane >> 2);
    const int koff = (lane & 3) * 8;
    int rA0 = m0 + rowT;       if (rA0 > M - 1) rA0 = M - 1;
    int rA1 = m0 + rowT + 64;  if (rA1 > M - 1) rA1 = M - 1;
    const u16* gA0 = A + (size_t)rA0 * lda + koff;
    const u16* gA1 = A + (size_t)rA1 * lda + koff;
    const u16* gB0 = Bt + (size_t)(n0 + rowT) * ldb + koff;
    const u16* gB1 = Bt + (size_t)(n0 + rowT + 64) * ldb + koff;
    u16* sA0 = &As[rowT * 32 + koff];
    u16* sA1 = &As[(rowT + 64) * 32 + koff];
    u16* sB0 = &Bs[rowT * 32 + koff];
    u16* sB1 = &Bs[(rowT + 64) * 32 + koff];

    const int nK = K >> 5;
    for (int kt = 0; kt < nK; ++kt) {
        ushort8v ta0 = *(const ushort8v*)gA0;
        ushort8v ta1 = *(const ushort8v*)gA1;
        ushort8v tb0 = *(const ushort8v*)gB0;
        ushort8v tb1 = *(const ushort8v*)gB1;
        gA0 += 32; gA1 += 32; gB0 += 32; gB1 += 32;
        __syncthreads();
        *(ushort8v*)sA0 = ta0;
        *(ushort8v*)sA1 = ta1;
        *(ushort8v*)sB0 = tb0;
        *(ushort8v*)sB1 = tb1;
        __syncthreads();
        short8v af[4], bf[4];
        #pragma unroll
        for (int i = 0; i < 4; ++i) af[i] = *(const short8v*)&As[(wm + 16 * i + r) * 32 + q * 8];
        #pragma unroll
        for (int j = 0; j < 4; ++j) bf[j] = *(const short8v*)&Bs[(wn + 16 * j + r) * 32 + q * 8];
        #pragma unroll
        for (int i = 0; i < 4; ++i)
            #pragma unroll
            for (int j = 0; j < 4; ++j)
                acc[i][j] = __builtin_amdgcn_mfma_f32_16x16x32_bf16(af[i], bf[j], acc[i][j], 0, 0, 0);
    }
    // C/D layout: col = lane&15, row = (lane>>4)*4 + reg  [verified m89/m91]
    #pragma unroll
    for (int i = 0; i < 4; ++i)
        #pragma unroll
        for (int j = 0; j < 4; ++j)
            #pragma unroll
            for (int rr = 0; rr < 4; ++rr) {
                size_t gr = (size_t)(m0 + wm + 16 * i + q * 4 + rr);
                int gc = n0 + wn + 16 * j + r;
                C[gr * ldc + gc] = f2bf(acc[i][j][rr]);
            }
}

// ---------------------------------------------------------------- attention dots
__global__ __launch_bounds__(256)
void attn_dots_kernel(const u16* __restrict__ xh, const u16* __restrict__ as_,
                      const u16* __restrict__ ad_, float* __restrict__ a_src,
                      float* __restrict__ a_dst, int n) {
    int v = blockIdx.x * 4 + (threadIdx.x >> 6);
    if (v >= n) return;
    const int lane = threadIdx.x & 63;
    const int h = lane >> 5;
    const int c0 = (lane & 31) * 8;
    ushort8v xv = *(const ushort8v*)&xh[(size_t)v * 512 + h * 256 + c0];
    ushort8v sv = *(const ushort8v*)&as_[h * 256 + c0];
    ushort8v dv = *(const ushort8v*)&ad_[h * 256 + c0];
    float ps = 0.f, pd = 0.f;
    #pragma unroll
    for (int k = 0; k < 8; ++k) {
        float x = bf2f(xv[k]);
        ps += x * bf2f(sv[k]);
        pd += x * bf2f(dv[k]);
    }
    #pragma unroll
    for (int d = 1; d < 32; d <<= 1) { ps += __shfl_xor(ps, d, 64); pd += __shfl_xor(pd, d, 64); }
    if ((lane & 31) == 0) { a_src[2 * v + h] = ps; a_dst[2 * v + h] = pd; }
}

// ---------------------------------------------------------------- GAT aggregate
__global__ __launch_bounds__(256)
void gat_agg_kernel(const u16* __restrict__ xh, const float* __restrict__ asrc,
                    const float* __restrict__ adst, const int* __restrict__ ptr,
                    const int* __restrict__ idx, const u16* __restrict__ bias,
                    u16* __restrict__ out, int ldo, int do_relu, int n, int Etot) {
    int v = blockIdx.x * 4 + (threadIdx.x >> 6);
    if (v >= n) return;
    const int lane = threadIdx.x & 63;
    const int head = lane >> 5;
    const int c0 = (lane & 31) * 8;
    int beg = ptr[v], end = ptr[v + 1];
    beg = min(max(beg, 0), Etot);
    end = min(max(end, beg), Etot);
    const float ad0 = adst[2 * v], ad1 = adst[2 * v + 1];
    const float es0 = leaky02(asrc[2 * v] + ad0);
    const float es1 = leaky02(asrc[2 * v + 1] + ad1);
    float m0 = es0, m1 = es1;
    for (int j = beg + lane; j < end; j += 64) {
        int s = idx[j]; s = ((unsigned)s < (unsigned)n) ? s : 0;
        m0 = fmaxf(m0, leaky02(asrc[2 * s] + ad0));
        m1 = fmaxf(m1, leaky02(asrc[2 * s + 1] + ad1));
    }
    #pragma unroll
    for (int d = 1; d < 64; d <<= 1) {
        m0 = fmaxf(m0, __shfl_xor(m0, d, 64));
        m1 = fmaxf(m1, __shfl_xor(m1, d, 64));
    }
    float s0 = 0.f, s1 = 0.f;
    for (int j = beg + lane; j < end; j += 64) {
        int s = idx[j]; s = ((unsigned)s < (unsigned)n) ? s : 0;
        s0 += __expf(leaky02(asrc[2 * s] + ad0) - m0);
        s1 += __expf(leaky02(asrc[2 * s + 1] + ad1) - m1);
    }
    #pragma unroll
    for (int d = 1; d < 64; d <<= 1) { s0 += __shfl_xor(s0, d, 64); s1 += __shfl_xor(s1, d, 64); }
    s0 += __expf(es0 - m0);
    s1 += __expf(es1 - m1);

    const float adh = head ? ad1 : ad0;
    const float mh = head ? m1 : m0;
    float facc[8] = {0.f, 0.f, 0.f, 0.f, 0.f, 0.f, 0.f, 0.f};
    for (int j = beg; j < end; ++j) {
        int s = idx[j]; s = ((unsigned)s < (unsigned)n) ? s : 0;
        float w = __expf(leaky02(asrc[2 * s + head] + adh) - mh);
        ushort8v f = *(const ushort8v*)&xh[(size_t)s * 512 + head * 256 + c0];
        #pragma unroll
        for (int k = 0; k < 8; ++k) facc[k] = fmaf(w, bf2f(f[k]), facc[k]);
    }
    {   // self-loop
        float w = __expf((head ? es1 : es0) - mh);
        ushort8v f = *(const ushort8v*)&xh[(size_t)v * 512 + head * 256 + c0];
        #pragma unroll
        for (int k = 0; k < 8; ++k) facc[k] = fmaf(w, bf2f(f[k]), facc[k]);
    }
    const float rinv = 0.5f / (head ? s1 : s0);   // normalize + head-mean
    #pragma unroll
    for (int k = 0; k < 8; ++k) facc[k] *= rinv;
    #pragma unroll
    for (int k = 0; k < 8; ++k) facc[k] += __shfl_xor(facc[k], 32, 64);
    if (lane < 32) {
        ushort8v bv = *(const ushort8v*)&bias[c0];
        ushort8v o;
        #pragma unroll
        for (int k = 0; k < 8; ++k) {
            float x = facc[k] + bf2f(bv[k]);
            if (do_relu) x = fmaxf(x, 0.f);
            o[k] = f2bf(x);
        }
        *(ushort8v*)&out[(size_t)v * ldo + c0] = o;
    }
}

// ---------------------------------------------------------------- gate (GRU-style)
// dest(bf16, ld 256) = z*x+(1-z)*h; optional d_out write (cols 0..256, ld 384, flag dtype)
__global__ __launch_bounds__(256)
void gate_kernel(const u16* __restrict__ logit, const u16* __restrict__ xb,
                 const u16* __restrict__ hb, const u16* __restrict__ fc1b,
                 const u16* __restrict__ fc2b, const u16* __restrict__ molb,
                 u16* __restrict__ dest, void* __restrict__ outw,
                 const int* __restrict__ flag, int n) {
    int i = blockIdx.x * 256 + threadIdx.x;
    if (i >= n) return;
    int node = i >> 5, c0 = (i & 31) * 8;
    ushort8v lg = *(const ushort8v*)&logit[(size_t)node * 256 + c0];
    ushort8v xv = *(const ushort8v*)&xb[(size_t)node * 256 + c0];
    ushort8v hv = *(const ushort8v*)&hb[(size_t)node * 256 + c0];
    ushort8v b1v = *(const ushort8v*)&fc1b[c0];
    ushort8v b2v = *(const ushort8v*)&fc2b[c0];
    ushort8v mbv = *(const ushort8v*)&molb[c0];
    float ov[8];
    ushort8v dv;
    #pragma unroll
    for (int k = 0; k < 8; ++k) {
        float l = bf2f(lg[k]) + bf2f(b1v[k]) + bf2f(b2v[k]) + bf2f(mbv[k]);
        float z = 1.f / (1.f + __expf(-l));
        ov[k] = z * bf2f(xv[k]) + (1.f - z) * bf2f(hv[k]);
        dv[k] = f2bf(ov[k]);
    }
    *(ushort8v*)&dest[(size_t)node * 256 + c0] = dv;
    if (outw) {
        if (*flag) {
            *(ushort8v*)((u16*)outw + (size_t)node * 384 + c0) = dv;
        } else {
            float* o = (float*)outw + (size_t)node * 384 + c0;
            #pragma unroll
            for (int k = 0; k < 8; ++k) o[k] = ov[k];
        }
    }
}

// ---------------------------------------------------------------- hypergraph gather
// res[v] = inv_deg * sum feat[idx[j]] (+bias, relu); F=128. Writes outb (bf16, ld ldo)
// and/or outw (d_out, ld 384, col offset col0, flag dtype).
__global__ __launch_bounds__(256)
void hyper_gather_kernel(const u16* __restrict__ feat, const int* __restrict__ ptr,
                         const int* __restrict__ idx, const u16* __restrict__ bias,
                         u16* __restrict__ outb, int ldo, void* __restrict__ outw,
                         int col0, const int* __restrict__ flag,
                         int do_relu, int n, int Etot) {
    int v = blockIdx.x * 4 + (threadIdx.x >> 6);
    if (v >= n) return;
    const int lane = threadIdx.x & 63;
    const int c0 = (lane & 15) * 8, sub = lane >> 4;
    int beg = ptr[v], end = ptr[v + 1];
    beg = min(max(beg, 0), Etot);
    end = min(max(end, beg), Etot);
    const float inv = (end > beg) ? 1.f / (float)(end - beg) : 0.f;
    float acc[8] = {0.f, 0.f, 0.f, 0.f, 0.f, 0.f, 0.f, 0.f};
    for (int j = beg + sub; j < end; j += 4) {
        int s = idx[j]; s = ((unsigned)s < (unsigned)n) ? s : 0;
        ushort8v f = *(const ushort8v*)&feat[(size_t)s * 128 + c0];
        #pragma unroll
        for (int k = 0; k < 8; ++k) acc[k] += bf2f(f[k]);
    }
    #pragma unroll
    for (int k = 0; k < 8; ++k) {
        acc[k] += __shfl_xor(acc[k], 16, 64);
        acc[k] += __shfl_xor(acc[k], 32, 64);
    }
    if (sub == 0) {
        float ov[8];
        ushort8v o;
        #pragma unroll
        for (int k = 0; k < 8; ++k) {
            float x = acc[k] * inv + (bias ? bf2f(bias[c0 + k]) : 0.f);
            if (do_relu) x = fmaxf(x, 0.f);
            ov[k] = x;
            o[k] = f2bf(x);
        }
        if (outb) *(ushort8v*)&outb[(size_t)v * ldo + c0] = o;
        if (outw) {
            if (*flag) {
                *(ushort8v*)((u16*)outw + (size_t)v * 384 + col0 + c0) = o;
            } else {
                float* ofp = (float*)outw + (size_t)v * 384 + col0 + c0;
                #pragma unroll
                for (int k = 0; k < 8; ++k) ofp[k] = ov[k];
            }
        }
    }
}

// ================================================================ launch
extern "C" void kernel_launch(void* const* d_in, const int* in_sizes, int n_in,
                              void* d_out, int out_size, void* d_ws, size_t ws_size,
                              hipStream_t stream) {
    const void* molx = d_in[0];
    const int*  ei   = (const int*)d_in[1];
    const void* W1 = d_in[3], *as1 = d_in[4], *ad1 = d_in[5], *b1 = d_in[6];
    const void* W2 = d_in[7], *as2 = d_in[8], *ad2 = d_in[9], *b2 = d_in[10];
    const void* W3 = d_in[11], *as3 = d_in[12], *ad3 = d_in[13], *b3 = d_in[14];
    const void* fc1w = d_in[15], *fc1b = d_in[16], *fc2w = d_in[17], *fc2b = d_in[18];
    const void* molb = d_in[19];
    const void* th1 = d_in[20], *hb1 = d_in[21], *th2 = d_in[22], *hb2 = d_in[23];
    (void)n_in; (void)out_size; (void)ws_size;

    const int N = in_sizes[0] / 78;
    const int E = in_sizes[1] / 2;
    const int Mp = ((N + 127) / 128) * 128;

    // ---- workspace: small/critical first, big feature buffers last (~236 MB)
    char* base = (char*)d_ws;
    size_t off = 0;
    auto alloc = [&](size_t bytes) -> void* {
        void* r = base + off;
        off = (off + bytes + 255) & ~(size_t)255;
        return r;
    };
    int* flag = (int*)alloc(4);
    u16* asv1 = (u16*)alloc(512 * 2); u16* adv1 = (u16*)alloc(512 * 2);
    u16* asv2 = (u16*)alloc(512 * 2); u16* adv2 = (u16*)alloc(512 * 2);
    u16* asv3 = (u16*)alloc(512 * 2); u16* adv3 = (u16*)alloc(512 * 2);
    u16* bv1 = (u16*)alloc(256 * 2); u16* bv2 = (u16*)alloc(256 * 2); u16* bv3 = (u16*)alloc(256 * 2);
    u16* fc1bv = (u16*)alloc(256 * 2); u16* fc2bv = (u16*)alloc(256 * 2); u16* molbv = (u16*)alloc(256 * 2);
    u16* hb1v = (u16*)alloc(128 * 2); u16* hb2v = (u16*)alloc(128 * 2);
    u16* W1t   = (u16*)alloc(512 * 96 * 2);
    u16* W2t   = (u16*)alloc(512 * 256 * 2);
    u16* W3t   = (u16*)alloc(512 * 256 * 2);
    u16* fc1wB = (u16*)alloc(256 * 256 * 2);
    u16* fc2wB = (u16*)alloc(256 * 256 * 2);
    u16* th1ta = (u16*)alloc(128 * 256 * 2);
    u16* th1tb = (u16*)alloc(128 * 96 * 2);
    u16* th2t  = (u16*)alloc(128 * 128 * 2);
    float* a_src = (float*)alloc((size_t)N * 2 * 4);
    float* a_dst = (float*)alloc((size_t)N * 2 * 4);
    int* deg_src = (int*)alloc((size_t)N * 4);
    int* deg_dst = (int*)alloc((size_t)N * 4);
    int* ptr_src = (int*)alloc((size_t)(N + 1) * 4);
    int* ptr_dst = (int*)alloc((size_t)(N + 1) * 4);
    int* cur_src = (int*)alloc((size_t)N * 4);
    int* cur_dst = (int*)alloc((size_t)N * 4);
    int* idx_src = (int*)alloc((size_t)E * 4);
    int* idx_dst = (int*)alloc((size_t)E * 4);
    u16* hbuf = (u16*)alloc((size_t)Mp * 256 * 2);   // molx-pad; h1; h2; h3
    u16* xbuf = (u16*)alloc((size_t)Mp * 256 * 2);   // x2; x3
    u16* xh   = (u16*)alloc((size_t)Mp * 512 * 2);   // xh / logits; hyper regions
    // hyper-phase regions carved from xh (Mp*224 + N*256 <= Mp*512):
    u16* R0 = xh;                                    // molx-pad (ld 96), Mp rows
    u16* R1 = xh + (size_t)Mp * 96;                  // xt (ld 128), Mp rows (GEMM C)
    u16* R2 = xh + (size_t)Mp * 224;                 // ef (ld 128), N rows
    u16* R3 = R2 + (size_t)N * 128;                  // hx1 (ld 128), N rows

    const int nodeBlocks = (N + 3) / 4;
    const int eBlocks = (E + 255) / 256;

    // ---- dtype detect (must precede all ingest kernels)
    detect_kernel<<<1, 256, 0, stream>>>((const unsigned*)molx, flag);

    // ---- CSR build
    hipMemsetAsync(deg_src, 0, (size_t)N * 4, stream);
    hipMemsetAsync(deg_dst, 0, (size_t)N * 4, stream);
    hist_kernel<<<eBlocks, 256, 0, stream>>>(ei, deg_src, deg_dst, E);
    scan_excl_kernel<<<1, 1024, 0, stream>>>(deg_src, ptr_src, N);
    scan_excl_kernel<<<1, 1024, 0, stream>>>(deg_dst, ptr_dst, N);
    copy2_kernel<<<(N + 255) / 256, 256, 0, stream>>>(ptr_src, cur_src, ptr_dst, cur_dst, N);
    fill_kernel<<<eBlocks, 256, 0, stream>>>(ei, cur_src, cur_dst, idx_src, idx_dst, E);

    // ---- ingest weights/vectors to canonical bf16
    auto itp = [&](const void* s, long bb, u16* d, int K, int Nc, int Kp) {
        ingest_transpose_kernel<<<(Nc * Kp + 255) / 256, 256, 0, stream>>>(s, bb, d, K, Nc, Kp, flag);
    };
    auto icp = [&](const void* s, u16* d, int n) {
        ingest_copy_kernel<<<(n + 255) / 256, 256, 0, stream>>>(s, d, n, flag);
    };
    itp(W1, 0, W1t, 78, 512, 96);
    itp(W2, 0, W2t, 256, 512, 256);
    itp(W3, 0, W3t, 256, 512, 256);
    itp(th1, 0, th1ta, 256, 128, 256);
    itp(th1, (long)256 * 128, th1tb, 78, 128, 96);
    itp(th2, 0, th2t, 128, 128, 128);
    icp(fc1w, fc1wB, 256 * 256);
    icp(fc2w, fc2wB, 256 * 256);
    icp(as1, asv1, 512); icp(ad1, adv1, 512);
    icp(as2, asv2, 512); icp(ad2, adv2, 512);
    icp(as3, asv3, 512); icp(ad3, adv3, 512);
    icp(b1, bv1, 256); icp(b2, bv2, 256); icp(b3, bv3, 256);
    icp(fc1b, fc1bv, 256); icp(fc2b, fc2bv, 256); icp(molb, molbv, 256);
    icp(hb1, hb1v, 128); icp(hb2, hb2v, 128);

    auto gemm = [&](const u16* A, int lda, const u16* Bt, int ldb, u16* C, int ldc,
                    int K, int Nc, int M, int beta) {
        dim3 g(Mp / 128, Nc / 128);
        gemm_kernel<<<g, 256, 0, stream>>>(A, lda, Bt, ldb, C, ldc, K, M, beta);
    };

    // ---- GAT layer 1: h1 = relu(gat(mol_x)) -> hbuf
    ingest_pad_molx_kernel<<<(N * 96 + 255) / 256, 256, 0, stream>>>(molx, hbuf, 256, N * 96, flag);
    gemm(hbuf, 256, W1t, 96, xh, 512, 96, 512, Mp, 0);
    attn_dots_kernel<<<nodeBlocks, 256, 0, stream>>>(xh, asv1, adv1, a_src, a_dst, N);
    gat_agg_kernel<<<nodeBlocks, 256, 0, stream>>>(xh, a_src, a_dst, ptr_dst, idx_dst,
                                                   bv1, hbuf, 256, 1, N, E);
    // ---- GAT layer 2: x2 = relu(gat(h1)); h2 = gate(x2,h1) in place
    gemm(hbuf, 256, W2t, 256, xh, 512, 256, 512, Mp, 0);
    attn_dots_kernel<<<nodeBlocks, 256, 0, stream>>>(xh, asv2, adv2, a_src, a_dst, N);
    gat_agg_kernel<<<nodeBlocks, 256, 0, stream>>>(xh, a_src, a_dst, ptr_dst, idx_dst,
                                                   bv2, xbuf, 256, 1, N, E);
    gemm(xbuf, 256, fc1wB, 256, xh, 256, 256, 256, Mp, 0);
    gemm(hbuf, 256, fc2wB, 256, xh, 256, 256, 256, Mp, 1);
    gate_kernel<<<(N * 32 + 255) / 256, 256, 0, stream>>>(xh, xbuf, hbuf, fc1bv, fc2bv,
                                                          molbv, hbuf, nullptr, flag, N * 32);
    // ---- GAT layer 3: x3 = gat(h2) (no relu); h3 = gate -> hbuf + d_out[:, :256]
    gemm(hbuf, 256, W3t, 256, xh, 512, 256, 512, Mp, 0);
    attn_dots_kernel<<<nodeBlocks, 256, 0, stream>>>(xh, asv3, adv3, a_src, a_dst, N);
    gat_agg_kernel<<<nodeBlocks, 256, 0, stream>>>(xh, a_src, a_dst, ptr_dst, idx_dst,
                                                   bv3, xbuf, 256, 0, N, E);
    gemm(xbuf, 256, fc1wB, 256, xh, 256, 256, 256, Mp, 0);
    gemm(hbuf, 256, fc2wB, 256, xh, 256, 256, 256, Mp, 1);
    gate_kernel<<<(N * 32 + 255) / 256, 256, 0, stream>>>(xh, xbuf, hbuf, fc1bv, fc2bv,
                                                          molbv, hbuf, d_out, flag, N * 32);
    // ---- Hypergraph layer 1: xt = [h3|molx] @ theta1 (accumulate), then 2 gathers
    ingest_pad_molx_kernel<<<(N * 96 + 255) / 256, 256, 0, stream>>>(molx, R0, 96, N * 96, flag);
    gemm(hbuf, 256, th1ta, 256, R1, 128, 256, 128, Mp, 0);
    gemm(R0, 96, th1tb, 96, R1, 128, 96, 128, N, 1);
    hyper_gather_kernel<<<nodeBlocks, 256, 0, stream>>>(R1, ptr_dst, idx_dst, (const u16*)nullptr,
                                                        R2, 128, nullptr, 0, flag, 0, N, E);
    hyper_gather_kernel<<<nodeBlocks, 256, 0, stream>>>(R2, ptr_src, idx_src, hb1v,
                                                        R3, 128, nullptr, 0, flag, 1, N, E);
    // ---- Hypergraph layer 2 -> d_out[:, 256:384]
    gemm(R3, 128, th2t, 128, R1, 128, 128, 128, N, 0);
    hyper_gather_kernel<<<nodeBlocks, 256, 0, stream>>>(R1, ptr_dst, idx_dst, (const u16*)nullptr,
                                                        R2, 128, nullptr, 0, flag, 0, N, E);
    hyper_gather_kernel<<<nodeBlocks, 256, 0, stream>>>(R2, ptr_src, idx_src, hb2v,
                                                        (u16*)nullptr, 0, d_out, 256, flag, 1, N, E);
}

// Round 4
// 3181.787 us; speedup vs baseline: 1.1796x; 1.1796x over previous
//
#include <hip/hip_runtime.h>

typedef unsigned short u16;
typedef __attribute__((ext_vector_type(8))) short short8v;    // MFMA A/B frag (8 bf16)
typedef __attribute__((ext_vector_type(8))) unsigned short ushort8v;
typedef __attribute__((ext_vector_type(4))) unsigned short ushort4v;
typedef __attribute__((ext_vector_type(4))) float f32x4;

__device__ __forceinline__ float bf2f(u16 u) {
    union { unsigned int i; float f; } v; v.i = ((unsigned int)u) << 16; return v.f;
}
__device__ __forceinline__ u16 f2bf(float f) {
    union { float f; unsigned int i; } v; v.f = f;
    unsigned int i = v.i;
    return (u16)((i + 0x7FFFu + ((i >> 16) & 1u)) >> 16);
}
__device__ __forceinline__ float leaky02(float x) { return x > 0.f ? x : 0.2f * x; }
// flag=1: input buffers are packed bf16; flag=0: fp32
__device__ __forceinline__ float load_in(const void* p, long i, int isbf) {
    return isbf ? bf2f(((const u16*)p)[i]) : ((const float*)p)[i];
}

// ---------------------------------------------------------------- dtype detect
__global__ void detect_kernel(const unsigned* __restrict__ w, int* __restrict__ flag) {
    __shared__ int cnt;
    int t = threadIdx.x;
    if (t == 0) cnt = 0;
    __syncthreads();
    unsigned x = w[t * 16];
    unsigned lo = x & 0xFFFFu;
    int e = (int)((x >> 7) & 0xFFu);
    int good = (lo == 0u) || (e >= 100 && e <= 140);
    atomicAdd(&cnt, good);
    __syncthreads();
    if (t == 0) *flag = (cnt > 128) ? 1 : 0;
}

// ---------------------------------------------------------------- CSR build
__global__ void hist_kernel(const int* __restrict__ ei, int* __restrict__ deg_src,
                            int* __restrict__ deg_dst, int E_) {
    int e = blockIdx.x * 256 + threadIdx.x;
    if (e >= E_) return;
    atomicAdd(&deg_src[ei[e]], 1);
    atomicAdd(&deg_dst[ei[E_ + e]], 1);
}

__global__ void scan_excl_kernel(const int* __restrict__ deg, int* __restrict__ ptr, int n) {
    __shared__ int s_woff[17];
    __shared__ int s_carry;
    const int t = threadIdx.x;          // 1024 threads
    const int lane = t & 63, wid = t >> 6;
    if (t == 0) s_carry = 0;
    __syncthreads();
    for (int base = 0; base < n; base += 1024) {
        int i = base + t;
        int v = (i < n) ? deg[i] : 0;
        int incl = v;
        #pragma unroll
        for (int d = 1; d < 64; d <<= 1) {
            int x = __shfl_up(incl, d, 64);
            if (lane >= d) incl += x;
        }
        if (lane == 63) s_woff[wid] = incl;
        __syncthreads();
        if (t == 0) {
            int run = 0;
            #pragma unroll
            for (int w = 0; w < 16; ++w) { int x = s_woff[w]; s_woff[w] = run; run += x; }
            s_woff[16] = run;
        }
        __syncthreads();
        int excl = s_carry + s_woff[wid] + incl - v;
        if (i < n) ptr[i] = excl;
        __syncthreads();
        if (t == 0) s_carry += s_woff[16];
        __syncthreads();
    }
    if (t == 0) ptr[n] = s_carry;
}

__global__ void copy2_kernel(const int* __restrict__ a, int* __restrict__ b,
                             const int* __restrict__ c, int* __restrict__ d2, int n) {
    int i = blockIdx.x * 256 + threadIdx.x;
    if (i < n) { b[i] = a[i]; d2[i] = c[i]; }
}

__global__ void fill_kernel(const int* __restrict__ ei, int* __restrict__ cur_src,
                            int* __restrict__ cur_dst, int* __restrict__ idx_src,
                            int* __restrict__ idx_dst, int E_) {
    int e = blockIdx.x * 256 + threadIdx.x;
    if (e >= E_) return;
    int s = ei[e], d = ei[E_ + e];
    int p = atomicAdd(&cur_dst[d], 1); idx_dst[p] = s;
    int q = atomicAdd(&cur_src[s], 1); idx_src[q] = d;
}

// ---------------------------------------------------------------- ingest (dtype-aware)
// src [K x Nc] row-major + elem base -> dst [Nc x Kp] bf16 (B^T), zero-pad k>=K
__global__ void ingest_transpose_kernel(const void* __restrict__ src, long base,
                                        u16* __restrict__ dst, int K, int Nc, int Kp,
                                        const int* __restrict__ flag) {
    int i = blockIdx.x * 256 + threadIdx.x;
    if (i >= Nc * Kp) return;
    int n = i / Kp, k = i - n * Kp;
    float v = (k < K) ? load_in(src, base + (long)k * Nc + n, *flag) : 0.f;
    dst[i] = f2bf(v);
}

__global__ void ingest_copy_kernel(const void* __restrict__ src, u16* __restrict__ dst,
                                   int n, const int* __restrict__ flag) {
    int i = blockIdx.x * 256 + threadIdx.x;
    if (i < n) dst[i] = f2bf(load_in(src, i, *flag));
}

// WcatT[o, h*Fh+c] = 0.5 * W[c, h*256+o]  (c<Kin else 0); o in [0,256). ld = 2*Fh.
__global__ void ingest_wcat_kernel(const void* __restrict__ W, u16* __restrict__ dst,
                                   int Kin, int Fh, const int* __restrict__ flag) {
    int i = blockIdx.x * 256 + threadIdx.x;
    int tot = 256 * 2 * Fh;
    if (i >= tot) return;
    int o = i / (2 * Fh), k = i - o * 2 * Fh;
    int h = k / Fh, c = k - h * Fh;
    float v = (c < Kin) ? 0.5f * load_in(W, (long)c * 512 + h * 256 + o, *flag) : 0.f;
    dst[i] = f2bf(v);
}

// BcatT[o, k] = k<256 ? fc1[o,k] : fc2[o,k-256]   (256 x 512)
__global__ void ingest_bcat_kernel(const void* __restrict__ fc1, const void* __restrict__ fc2,
                                   u16* __restrict__ dst, const int* __restrict__ flag) {
    int i = blockIdx.x * 256 + threadIdx.x;
    if (i >= 256 * 512) return;
    int o = i >> 9, k = i & 511;
    float v = (k < 256) ? load_in(fc1, (long)o * 256 + k, *flag)
                        : load_in(fc2, (long)o * 256 + k - 256, *flag);
    dst[i] = f2bf(v);
}

// dst[r*ldd + c] = c<78 ? molx[r*78+c] : 0  for c in [0,96)
__global__ void ingest_pad_molx_kernel(const void* __restrict__ x, u16* __restrict__ dst,
                                       int ldd, int total, const int* __restrict__ flag) {
    int i = blockIdx.x * 256 + threadIdx.x;
    if (i >= total) return;
    int r = i / 96, c = i - r * 96;
    float v = (c < 78) ? load_in(x, (long)r * 78 + c, *flag) : 0.f;
    dst[(size_t)r * ldd + c] = f2bf(v);
}

// was[h*Fh+c] = sum_o W[c, h*256+o] * as[h*256+o]; wad same with ad. fp32 out.
__global__ void attn_vec_kernel(const void* __restrict__ W, const void* __restrict__ as_,
                                const void* __restrict__ ad_, float* __restrict__ was,
                                float* __restrict__ wad, int Kin, int Fh,
                                const int* __restrict__ flag) {
    int i = blockIdx.x * 256 + threadIdx.x;
    if (i >= 2 * Fh) return;
    int h = i / Fh, c = i - h * Fh;
    float s = 0.f, d = 0.f;
    if (c < Kin) {
        int f = *flag;
        for (int o = 0; o < 256; ++o) {
            float w = load_in(W, (long)c * 512 + h * 256 + o, f);
            s += w * load_in(as_, h * 256 + o, f);
            d += w * load_in(ad_, h * 256 + o, f);
        }
    }
    was[i] = s; wad[i] = d;
}

// ---------------------------------------------------------------- GEMM (bf16 MFMA)
// C[Mp x Nc] = A[<=M x K] * Bt[Nc x K]^T (+C if beta) (+bias, relu); row clamp to M-1.
__global__ __launch_bounds__(256, 2)
void gemm_kernel(const u16* __restrict__ A, int lda,
                 const u16* __restrict__ Bt, int ldb,
                 u16* __restrict__ C, int ldc, int K, int M, int beta,
                 const u16* __restrict__ bias, int relu) {
    __shared__ __align__(16) u16 As[128 * 32];
    __shared__ __align__(16) u16 Bs[128 * 32];
    const int tid = threadIdx.x;
    const int wave = tid >> 6, lane = tid & 63;
    const int m0 = blockIdx.x * 128;
    const int n0 = blockIdx.y * 128;
    const int wm = (wave & 1) * 64, wn = (wave >> 1) * 64;
    const int r = lane & 15, q = lane >> 4;

    f32x4 acc[4][4];
    if (beta) {
        #pragma unroll
        for (int i = 0; i < 4; ++i)
            #pragma unroll
            for (int j = 0; j < 4; ++j)
                #pragma unroll
                for (int rr = 0; rr < 4; ++rr) {
                    size_t gr = (size_t)(m0 + wm + 16 * i + q * 4 + rr);
                    int gc = n0 + wn + 16 * j + r;
                    acc[i][j][rr] = bf2f(C[gr * ldc + gc]);
                }
    } else {
        #pragma unroll
        for (int i = 0; i < 4; ++i)
            #pragma unroll
            for (int j = 0; j < 4; ++j) acc[i][j] = (f32x4)0.f;
    }

    const int rowT = wave * 16 + (lane >> 2);
    const int koff = (lane & 3) * 8;
    int rA0 = m0 + rowT;       if (rA0 > M - 1) rA0 = M - 1;
    int rA1 = m0 + rowT + 64;  if (rA1 > M - 1) rA1 = M - 1;
    const u16* gA0 = A + (size_t)rA0 * lda + koff;
    const u16* gA1 = A + (size_t)rA1 * lda + koff;
    const u16* gB0 = Bt + (size_t)(n0 + rowT) * ldb + koff;
    const u16* gB1 = Bt + (size_t)(n0 + rowT + 64) * ldb + koff;
    u16* sA0 = &As[rowT * 32 + koff];
    u16* sA1 = &As[(rowT + 64) * 32 + koff];
    u16* sB0 = &Bs[rowT * 32 + koff];
    u16* sB1 = &Bs[(rowT + 64) * 32 + koff];

    const int nK = K >> 5;
    for (int kt = 0; kt < nK; ++kt) {
        ushort8v ta0 = *(const ushort8v*)gA0;
        ushort8v ta1 = *(const ushort8v*)gA1;
        ushort8v tb0 = *(const ushort8v*)gB0;
        ushort8v tb1 = *(const ushort8v*)gB1;
        gA0 += 32; gA1 += 32; gB0 += 32; gB1 += 32;
        __syncthreads();
        *(ushort8v*)sA0 = ta0;
        *(ushort8v*)sA1 = ta1;
        *(ushort8v*)sB0 = tb0;
        *(ushort8v*)sB1 = tb1;
        __syncthreads();
        short8v af[4], bf[4];
        #pragma unroll
        for (int i = 0; i < 4; ++i) af[i] = *(const short8v*)&As[(wm + 16 * i + r) * 32 + q * 8];
        #pragma unroll
        for (int j = 0; j < 4; ++j) bf[j] = *(const short8v*)&Bs[(wn + 16 * j + r) * 32 + q * 8];
        #pragma unroll
        for (int i = 0; i < 4; ++i)
            #pragma unroll
            for (int j = 0; j < 4; ++j)
                acc[i][j] = __builtin_amdgcn_mfma_f32_16x16x32_bf16(af[i], bf[j], acc[i][j], 0, 0, 0);
    }
    // C/D layout: col = lane&15, row = (lane>>4)*4 + reg
    #pragma unroll
    for (int j = 0; j < 4; ++j) {
        int gc = n0 + wn + 16 * j + r;
        float bv = bias ? bf2f(bias[gc]) : 0.f;
        #pragma unroll
        for (int i = 0; i < 4; ++i)
            #pragma unroll
            for (int rr = 0; rr < 4; ++rr) {
                size_t gr = (size_t)(m0 + wm + 16 * i + q * 4 + rr);
                float x = acc[i][j][rr] + bv;
                if (relu) x = fmaxf(x, 0.f);
                C[gr * ldc + gc] = f2bf(x);
            }
    }
}

// ---------------------------------------------------------------- attention dots (h-space)
// a_src[2v+h] = sum_c h[v,c] * was[h*Fh+c]; a_dst same with wad. 1 wave/node.
__global__ __launch_bounds__(256)
void attn_dots_h_kernel(const u16* __restrict__ hsrc, int ldh,
                        const float* __restrict__ was, const float* __restrict__ wad,
                        float* __restrict__ a_src, float* __restrict__ a_dst,
                        int Fh, int n) {
    int v = blockIdx.x * 4 + (threadIdx.x >> 6);
    if (v >= n) return;
    const int lane = threadIdx.x & 63;
    const int c0 = lane * 4;
    float ps0 = 0.f, pd0 = 0.f, ps1 = 0.f, pd1 = 0.f;
    if (c0 < Fh) {
        ushort4v xv = *(const ushort4v*)&hsrc[(size_t)v * ldh + c0];
        #pragma unroll
        for (int k = 0; k < 4; ++k) {
            float x = bf2f(xv[k]);
            ps0 += x * was[c0 + k];
            pd0 += x * wad[c0 + k];
            ps1 += x * was[Fh + c0 + k];
            pd1 += x * wad[Fh + c0 + k];
        }
    }
    #pragma unroll
    for (int d = 1; d < 64; d <<= 1) {
        ps0 += __shfl_xor(ps0, d, 64); pd0 += __shfl_xor(pd0, d, 64);
        ps1 += __shfl_xor(ps1, d, 64); pd1 += __shfl_xor(pd1, d, 64);
    }
    if (lane == 0) {
        a_src[2 * v] = ps0; a_src[2 * v + 1] = ps1;
        a_dst[2 * v] = pd0; a_dst[2 * v + 1] = pd1;
    }
}

// ---------------------------------------------------------------- GAT aggregate (h-space)
// agg[v, h*F + c] = (1/s_h) * (sum_e alpha_eh * hsrc[src_e, c] + self). F = 96|256.
// Softmax over incoming edges + implicit self-loop. 1 wave/node, 2 edges in flight.
__global__ __launch_bounds__(256)
void gat_agg_h_kernel(const u16* __restrict__ hsrc, int ldh, int F,
                      const float* __restrict__ asrc, const float* __restrict__ adst,
                      const int* __restrict__ ptr, const int* __restrict__ idx,
                      u16* __restrict__ agg, int ldagg, int n, int Etot) {
    int v = blockIdx.x * 4 + (threadIdx.x >> 6);
    if (v >= n) return;
    const int lane = threadIdx.x & 63;
    const int sub = lane >> 5;            // half-wave = edge parity
    const int c0 = (lane & 31) * 8;       // 8 cols per lane
    const int act = (c0 < F);
    int beg = ptr[v], end = ptr[v + 1];
    beg = min(max(beg, 0), Etot);
    end = min(max(end, beg), Etot);
    const float ad0 = adst[2 * v], ad1 = adst[2 * v + 1];
    const float es0 = leaky02(asrc[2 * v] + ad0);
    const float es1 = leaky02(asrc[2 * v + 1] + ad1);
    // pass 1: max
    float m0 = es0, m1 = es1;
    for (int j = beg + lane; j < end; j += 64) {
        int s = idx[j]; s = ((unsigned)s < (unsigned)n) ? s : 0;
        m0 = fmaxf(m0, leaky02(asrc[2 * s] + ad0));
        m1 = fmaxf(m1, leaky02(asrc[2 * s + 1] + ad1));
    }
    #pragma unroll
    for (int d = 1; d < 64; d <<= 1) {
        m0 = fmaxf(m0, __shfl_xor(m0, d, 64));
        m1 = fmaxf(m1, __shfl_xor(m1, d, 64));
    }
    // pass 2: sum of exp
    float s0 = 0.f, s1 = 0.f;
    for (int j = beg + lane; j < end; j += 64) {
        int s = idx[j]; s = ((unsigned)s < (unsigned)n) ? s : 0;
        s0 += __expf(leaky02(asrc[2 * s] + ad0) - m0);
        s1 += __expf(leaky02(asrc[2 * s + 1] + ad1) - m1);
    }
    #pragma unroll
    for (int d = 1; d < 64; d <<= 1) { s0 += __shfl_xor(s0, d, 64); s1 += __shfl_xor(s1, d, 64); }
    s0 += __expf(es0 - m0);
    s1 += __expf(es1 - m1);
    // pass 3: weighted h gather, 2 edges/wave (half-wave each), unroll 2
    float f0a[8] = {0,0,0,0,0,0,0,0};
    float f1a[8] = {0,0,0,0,0,0,0,0};
    int j = beg + sub;
    for (; j + 2 < end; j += 4) {
        int sA = idx[j];     sA = ((unsigned)sA < (unsigned)n) ? sA : 0;
        int sB = idx[j + 2]; sB = ((unsigned)sB < (unsigned)n) ? sB : 0;
        float wA0 = __expf(leaky02(asrc[2 * sA] + ad0) - m0);
        float wA1 = __expf(leaky02(asrc[2 * sA + 1] + ad1) - m1);
        float wB0 = __expf(leaky02(asrc[2 * sB] + ad0) - m0);
        float wB1 = __expf(leaky02(asrc[2 * sB + 1] + ad1) - m1);
        if (act) {
            ushort8v fA = *(const ushort8v*)&hsrc[(size_t)sA * ldh + c0];
            ushort8v fB = *(const ushort8v*)&hsrc[(size_t)sB * ldh + c0];
            #pragma unroll
            for (int k = 0; k < 8; ++k) {
                float xA = bf2f(fA[k]), xB = bf2f(fB[k]);
                f0a[k] += wA0 * xA + wB0 * xB;
                f1a[k] += wA1 * xA + wB1 * xB;
            }
        }
    }
    for (; j < end; j += 2) {
        int s = idx[j]; s = ((unsigned)s < (unsigned)n) ? s : 0;
        float w0 = __expf(leaky02(asrc[2 * s] + ad0) - m0);
        float w1 = __expf(leaky02(asrc[2 * s + 1] + ad1) - m1);
        if (act) {
            ushort8v f = *(const ushort8v*)&hsrc[(size_t)s * ldh + c0];
            #pragma unroll
            for (int k = 0; k < 8; ++k) {
                float x = bf2f(f[k]);
                f0a[k] += w0 * x;
                f1a[k] += w1 * x;
            }
        }
    }
    if (sub == 0 && act) {   // self-loop
        float w0 = __expf(es0 - m0), w1 = __expf(es1 - m1);
        ushort8v f = *(const ushort8v*)&hsrc[(size_t)v * ldh + c0];
        #pragma unroll
        for (int k = 0; k < 8; ++k) {
            float x = bf2f(f[k]);
            f0a[k] += w0 * x;
            f1a[k] += w1 * x;
        }
    }
    #pragma unroll
    for (int k = 0; k < 8; ++k) {
        f0a[k] += __shfl_xor(f0a[k], 32, 64);
        f1a[k] += __shfl_xor(f1a[k], 32, 64);
    }
    if (lane < 32 && act) {
        const float i0 = 1.f / s0, i1 = 1.f / s1;
        ushort8v o0, o1;
        #pragma unroll
        for (int k = 0; k < 8; ++k) { o0[k] = f2bf(f0a[k] * i0); o1[k] = f2bf(f1a[k] * i1); }
        *(ushort8v*)&agg[(size_t)v * ldagg + c0] = o0;
        *(ushort8v*)&agg[(size_t)v * ldagg + F + c0] = o1;
    }
}

// ---------------------------------------------------------------- gate (GRU-style)
// dest[v,:](ld 512) = z*x+(1-z)*h where x=cat[v,0:256], h=cat[v,256:512];
// z = sigmoid(logit + fc1_b + fc2_b + mol_bias). Optional d_out write (ld 384).
__global__ __launch_bounds__(256)
void gate_kernel(const u16* __restrict__ logit, const u16* __restrict__ cat,
                 const u16* __restrict__ fc1b, const u16* __restrict__ fc2b,
                 const u16* __restrict__ molb, u16* __restrict__ dest,
                 void* __restrict__ outw, const int* __restrict__ flag, int n) {
    int i = blockIdx.x * 256 + threadIdx.x;
    if (i >= n) return;
    int node = i >> 5, c0 = (i & 31) * 8;
    ushort8v lg = *(const ushort8v*)&logit[(size_t)node * 256 + c0];
    ushort8v xv = *(const ushort8v*)&cat[(size_t)node * 512 + c0];
    ushort8v hv = *(const ushort8v*)&cat[(size_t)node * 512 + 256 + c0];
    ushort8v b1v = *(const ushort8v*)&fc1b[c0];
    ushort8v b2v = *(const ushort8v*)&fc2b[c0];
    ushort8v mbv = *(const ushort8v*)&molb[c0];
    float ov[8];
    ushort8v dv;
    #pragma unroll
    for (int k = 0; k < 8; ++k) {
        float l = bf2f(lg[k]) + bf2f(b1v[k]) + bf2f(b2v[k]) + bf2f(mbv[k]);
        float z = 1.f / (1.f + __expf(-l));
        ov[k] = z * bf2f(xv[k]) + (1.f - z) * bf2f(hv[k]);
        dv[k] = f2bf(ov[k]);
    }
    *(ushort8v*)&dest[(size_t)node * 512 + c0] = dv;
    if (outw) {
        if (*flag) {
            *(ushort8v*)((u16*)outw + (size_t)node * 384 + c0) = dv;
        } else {
            float* o = (float*)outw + (size_t)node * 384 + c0;
            #pragma unroll
            for (int k = 0; k < 8; ++k) o[k] = ov[k];
        }
    }
}

// ---------------------------------------------------------------- hypergraph gather
// res[v] = inv_deg * sum feat[idx[j]] (+bias, relu); F=128 fixed.
__global__ __launch_bounds__(256)
void hyper_gather_kernel(const u16* __restrict__ feat, const int* __restrict__ ptr,
                         const int* __restrict__ idx, const u16* __restrict__ bias,
                         u16* __restrict__ outb, int ldo, void* __restrict__ outw,
                         int col0, const int* __restrict__ flag,
                         int do_relu, int n, int Etot) {
    int v = blockIdx.x * 4 + (threadIdx.x >> 6);
    if (v >= n) return;
    const int lane = threadIdx.x & 63;
    const int c0 = (lane & 15) * 8, sub = lane >> 4;
    int beg = ptr[v], end = ptr[v + 1];
    beg = min(max(beg, 0), Etot);
    end = min(max(end, beg), Etot);
    const float inv = (end > beg) ? 1.f / (float)(end - beg) : 0.f;
    float acc[8] = {0,0,0,0,0,0,0,0};
    for (int j = beg + sub; j < end; j += 4) {
        int s = idx[j]; s = ((unsigned)s < (unsigned)n) ? s : 0;
        ushort8v f = *(const ushort8v*)&feat[(size_t)s * 128 + c0];
        #pragma unroll
        for (int k = 0; k < 8; ++k) acc[k] += bf2f(f[k]);
    }
    #pragma unroll
    for (int k = 0; k < 8; ++k) {
        acc[k] += __shfl_xor(acc[k], 16, 64);
        acc[k] += __shfl_xor(acc[k], 32, 64);
    }
    if (sub == 0) {
        float ov[8];
        ushort8v o;
        #pragma unroll
        for (int k = 0; k < 8; ++k) {
            float x = acc[k] * inv + (bias ? bf2f(bias[c0 + k]) : 0.f);
            if (do_relu) x = fmaxf(x, 0.f);
            ov[k] = x;
            o[k] = f2bf(x);
        }
        if (outb) *(ushort8v*)&outb[(size_t)v * ldo + c0] = o;
        if (outw) {
            if (*flag) {
                *(ushort8v*)((u16*)outw + (size_t)v * 384 + col0 + c0) = o;
            } else {
                float* ofp = (float*)outw + (size_t)v * 384 + col0 + c0;
                #pragma unroll
                for (int k = 0; k < 8; ++k) ofp[k] = ov[k];
            }
        }
    }
}

// ================================================================ launch
extern "C" void kernel_launch(void* const* d_in, const int* in_sizes, int n_in,
                              void* d_out, int out_size, void* d_ws, size_t ws_size,
                              hipStream_t stream) {
    const void* molx = d_in[0];
    const int*  ei   = (const int*)d_in[1];
    const void* W1 = d_in[3], *as1 = d_in[4], *ad1 = d_in[5], *b1 = d_in[6];
    const void* W2 = d_in[7], *as2 = d_in[8], *ad2 = d_in[9], *b2 = d_in[10];
    const void* W3 = d_in[11], *as3 = d_in[12], *ad3 = d_in[13], *b3 = d_in[14];
    const void* fc1w = d_in[15], *fc1b = d_in[16], *fc2w = d_in[17], *fc2b = d_in[18];
    const void* molb = d_in[19];
    const void* th1 = d_in[20], *hb1 = d_in[21], *th2 = d_in[22], *hb2 = d_in[23];
    (void)n_in; (void)out_size; (void)ws_size;

    const int N = in_sizes[0] / 78;
    const int E = in_sizes[1] / 2;
    const int Mp = ((N + 127) / 128) * 128;

    // ---- workspace (~236 MB @ N=100000, same envelope as passing round)
    char* base = (char*)d_ws;
    size_t off = 0;
    auto alloc = [&](size_t bytes) -> void* {
        void* r = base + off;
        off = (off + bytes + 255) & ~(size_t)255;
        return r;
    };
    int* flag = (int*)alloc(4);
    u16* bv1 = (u16*)alloc(256 * 2); u16* bv2 = (u16*)alloc(256 * 2); u16* bv3 = (u16*)alloc(256 * 2);
    u16* fc1bv = (u16*)alloc(256 * 2); u16* fc2bv = (u16*)alloc(256 * 2); u16* molbv = (u16*)alloc(256 * 2);
    u16* hb1v = (u16*)alloc(128 * 2); u16* hb2v = (u16*)alloc(128 * 2);
    float* was1 = (float*)alloc(192 * 4); float* wad1 = (float*)alloc(192 * 4);
    float* was2 = (float*)alloc(512 * 4); float* wad2 = (float*)alloc(512 * 4);
    float* was3 = (float*)alloc(512 * 4); float* wad3 = (float*)alloc(512 * 4);
    u16* Wc1 = (u16*)alloc(256 * 192 * 2);
    u16* Wc2 = (u16*)alloc(256 * 512 * 2);
    u16* Wc3 = (u16*)alloc(256 * 512 * 2);
    u16* Bcat = (u16*)alloc(256 * 512 * 2);
    u16* th1ta = (u16*)alloc(128 * 256 * 2);
    u16* th1tb = (u16*)alloc(128 * 96 * 2);
    u16* th2t  = (u16*)alloc(128 * 128 * 2);
    float* a_src = (float*)alloc((size_t)N * 2 * 4);
    float* a_dst = (float*)alloc((size_t)N * 2 * 4);
    int* deg_src = (int*)alloc((size_t)N * 4);
    int* deg_dst = (int*)alloc((size_t)N * 4);
    int* ptr_src = (int*)alloc((size_t)(N + 1) * 4);
    int* ptr_dst = (int*)alloc((size_t)(N + 1) * 4);
    int* cur_src = (int*)alloc((size_t)N * 4);
    int* cur_dst = (int*)alloc((size_t)N * 4);
    int* idx_src = (int*)alloc((size_t)E * 4);
    int* idx_dst = (int*)alloc((size_t)E * 4);
    u16* cat = (u16*)alloc((size_t)Mp * 512 * 2);   // [x | h] per row (ld 512)
    u16* agg = (u16*)alloc((size_t)Mp * 512 * 2);   // agg / logits / hyper regions
    // hyper-phase regions inside agg:
    u16* xt   = agg;                         // Mp x 128
    u16* efb  = agg + (size_t)Mp * 128;      // N x 128
    u16* hx1  = agg + (size_t)Mp * 256;      // N x 128
    u16* mxp2 = agg + (size_t)Mp * 384;      // Mp x 96 (re-ingested mol_x for hyper GEMM)

    const int nodeBlocks = (N + 3) / 4;
    const int eBlocks = (E + 255) / 256;

    // ---- dtype detect (precedes all ingest)
    detect_kernel<<<1, 256, 0, stream>>>((const unsigned*)molx, flag);

    // ---- CSR build
    hipMemsetAsync(deg_src, 0, (size_t)N * 4, stream);
    hipMemsetAsync(deg_dst, 0, (size_t)N * 4, stream);
    hist_kernel<<<eBlocks, 256, 0, stream>>>(ei, deg_src, deg_dst, E);
    scan_excl_kernel<<<1, 1024, 0, stream>>>(deg_src, ptr_src, N);
    scan_excl_kernel<<<1, 1024, 0, stream>>>(deg_dst, ptr_dst, N);
    copy2_kernel<<<(N + 255) / 256, 256, 0, stream>>>(ptr_src, cur_src, ptr_dst, cur_dst, N);
    fill_kernel<<<eBlocks, 256, 0, stream>>>(ei, cur_src, cur_dst, idx_src, idx_dst, E);

    // ---- weight/vector ingest
    ingest_wcat_kernel<<<(256 * 192 + 255) / 256, 256, 0, stream>>>(W1, Wc1, 78, 96, flag);
    ingest_wcat_kernel<<<(256 * 512 + 255) / 256, 256, 0, stream>>>(W2, Wc2, 256, 256, flag);
    ingest_wcat_kernel<<<(256 * 512 + 255) / 256, 256, 0, stream>>>(W3, Wc3, 256, 256, flag);
    ingest_bcat_kernel<<<(256 * 512 + 255) / 256, 256, 0, stream>>>(fc1w, fc2w, Bcat, flag);
    ingest_transpose_kernel<<<(128 * 256 + 255) / 256, 256, 0, stream>>>(th1, 0, th1ta, 256, 128, 256, flag);
    ingest_transpose_kernel<<<(128 * 96 + 255) / 256, 256, 0, stream>>>(th1, (long)256 * 128, th1tb, 78, 128, 96, flag);
    ingest_transpose_kernel<<<(128 * 128 + 255) / 256, 256, 0, stream>>>(th2, 0, th2t, 128, 128, 128, flag);
    attn_vec_kernel<<<1, 256, 0, stream>>>(W1, as1, ad1, was1, wad1, 78, 96, flag);
    attn_vec_kernel<<<2, 256, 0, stream>>>(W2, as2, ad2, was2, wad2, 256, 256, flag);
    attn_vec_kernel<<<2, 256, 0, stream>>>(W3, as3, ad3, was3, wad3, 256, 256, flag);
    ingest_copy_kernel<<<1, 256, 0, stream>>>(b1, bv1, 256, flag);
    ingest_copy_kernel<<<1, 256, 0, stream>>>(b2, bv2, 256, flag);
    ingest_copy_kernel<<<1, 256, 0, stream>>>(b3, bv3, 256, flag);
    ingest_copy_kernel<<<1, 256, 0, stream>>>(fc1b, fc1bv, 256, flag);
    ingest_copy_kernel<<<1, 256, 0, stream>>>(fc2b, fc2bv, 256, flag);
    ingest_copy_kernel<<<1, 256, 0, stream>>>(molb, molbv, 256, flag);
    ingest_copy_kernel<<<1, 128, 0, stream>>>(hb1, hb1v, 128, flag);
    ingest_copy_kernel<<<1, 128, 0, stream>>>(hb2, hb2v, 128, flag);
    // mol_x padded into cat cols [0,96) (x-region unused until layer 2)
    ingest_pad_molx_kernel<<<(N * 96 + 255) / 256, 256, 0, stream>>>(molx, cat, 512, N * 96, flag);

    auto gemm = [&](const u16* A, int lda, const u16* Bt, int ldb, u16* C, int ldc,
                    int K, int Nc, int M, int beta, const u16* bias, int relu) {
        dim3 g(Mp / 128, Nc / 128);
        gemm_kernel<<<g, 256, 0, stream>>>(A, lda, Bt, ldb, C, ldc, K, M, beta, bias, relu);
    };

    // ---- GAT layer 1: agg over mol_x (F=96) -> h1 = relu(agg@Wc1 + b1) -> cat.h
    attn_dots_h_kernel<<<nodeBlocks, 256, 0, stream>>>(cat, 512, was1, wad1, a_src, a_dst, 96, N);
    gat_agg_h_kernel<<<nodeBlocks, 256, 0, stream>>>(cat, 512, 96, a_src, a_dst,
                                                     ptr_dst, idx_dst, agg, 192, N, E);
    gemm(agg, 192, Wc1, 192, cat + 256, 512, 192, 256, Mp, 0, bv1, 1);
    // ---- GAT layer 2: agg over h1 -> x2 = relu(agg@Wc2 + b2) -> cat.x; gate -> cat.h
    attn_dots_h_kernel<<<nodeBlocks, 256, 0, stream>>>(cat + 256, 512, was2, wad2, a_src, a_dst, 256, N);
    gat_agg_h_kernel<<<nodeBlocks, 256, 0, stream>>>(cat + 256, 512, 256, a_src, a_dst,
                                                     ptr_dst, idx_dst, agg, 512, N, E);
    gemm(agg, 512, Wc2, 512, cat, 512, 512, 256, Mp, 0, bv2, 1);
    gemm(cat, 512, Bcat, 512, agg /*logits*/, 256, 512, 256, Mp, 0, nullptr, 0);
    gate_kernel<<<(N * 32 + 255) / 256, 256, 0, stream>>>(agg, cat, fc1bv, fc2bv, molbv,
                                                          cat + 256, nullptr, flag, N * 32);
    // ---- GAT layer 3: x3 = agg@Wc3 + b3 (no relu); gate -> cat.h + d_out[:, :256]
    attn_dots_h_kernel<<<nodeBlocks, 256, 0, stream>>>(cat + 256, 512, was3, wad3, a_src, a_dst, 256, N);
    gat_agg_h_kernel<<<nodeBlocks, 256, 0, stream>>>(cat + 256, 512, 256, a_src, a_dst,
                                                     ptr_dst, idx_dst, agg, 512, N, E);
    gemm(agg, 512, Wc3, 512, cat, 512, 512, 256, Mp, 0, bv3, 0);
    gemm(cat, 512, Bcat, 512, agg /*logits*/, 256, 512, 256, Mp, 0, nullptr, 0);
    gate_kernel<<<(N * 32 + 255) / 256, 256, 0, stream>>>(agg, cat, fc1bv, fc2bv, molbv,
                                                          cat + 256, d_out, flag, N * 32);
    // ---- Hypergraph layer 1: xt = [h3|molx] @ theta1 (two passes), 2 gathers
    ingest_pad_molx_kernel<<<(N * 96 + 255) / 256, 256, 0, stream>>>(molx, mxp2, 96, N * 96, flag);
    gemm(cat + 256, 512, th1ta, 256, xt, 128, 256, 128, Mp, 0, nullptr, 0);
    gemm(mxp2, 96, th1tb, 96, xt, 128, 96, 128, Mp, 1, nullptr, 0);
    hyper_gather_kernel<<<nodeBlocks, 256, 0, stream>>>(xt, ptr_dst, idx_dst, (const u16*)nullptr,
                                                        efb, 128, nullptr, 0, flag, 0, N, E);
    hyper_gather_kernel<<<nodeBlocks, 256, 0, stream>>>(efb, ptr_src, idx_src, hb1v,
                                                        hx1, 128, nullptr, 0, flag, 1, N, E);
    // ---- Hypergraph layer 2 -> d_out[:, 256:384]
    gemm(hx1, 128, th2t, 128, xt, 128, 128, 128, Mp, 0, nullptr, 0);
    hyper_gather_kernel<<<nodeBlocks, 256, 0, stream>>>(xt, ptr_dst, idx_dst, (const u16*)nullptr,
                                                        efb, 128, nullptr, 0, flag, 0, N, E);
    hyper_gather_kernel<<<nodeBlocks, 256, 0, stream>>>(efb, ptr_src, idx_src, hb2v,
                                                        (u16*)nullptr, 0, d_out, 256, flag, 1, N, E);
}